// Round 5
// baseline (262.926 us; speedup 1.0000x reference)
//
#include <hip/hip_runtime.h>
#include <hip/hip_bf16.h>
#include <stdint.h>

// Shapes: N=32, CIN=COUT=64, T=256, V=25, K3=3, G=8
// GCN folded to one GEMM: M=1600 (m=w*64+c), K=1600 (k=cin*25+v), N=8192 (n,t)
//   residual (+x) folded into U's diagonal: U[w*64+c][c*25+w] += 1
// TCN: MFMA im2col GEMM: M=64 (o), K=576 (i,j), N=204800 (n,t,v)

typedef const float* fp;
typedef __attribute__((ext_vector_type(8))) short short8;   // 8 bf16 (4 VGPRs)
typedef __attribute__((ext_vector_type(4))) float floatx4;  // MFMA acc

__device__ __forceinline__ float us2f(unsigned int u){
  union { unsigned int i; float f; } c; c.i = u << 16; return c.f;
}
__device__ __forceinline__ unsigned short f2us(float f){
  __hip_bfloat16 h = __float2bfloat16(f);
  return *reinterpret_cast<unsigned short*>(&h);
}
__device__ __forceinline__ void gload_lds16(const void* g, void* l){
  __builtin_amdgcn_global_load_lds(
      (const __attribute__((address_space(1))) void*)g,
      (__attribute__((address_space(3))) void*)l, 16, 0, 0);
}

// ---------------- workspace layout (bytes) ----------------
// normA fp32 [3][8][25][28] @ 0         (67200)
// Weff  fp32 [64][192]      @ 67584     (49152)
// beff  fp32 [192]          @ 116736    (768)
// cbe   fp32 [64]           @ 117504    (256)
// cwetb bf16 [64][9][64]    @ 117760    (73728)
// biasU fp32 [1600]         @ 191488    (6400)
// U     bf16 [1664][1600]   @ 197888    (5324800)
// xb    bf16 [32][256][1600]@ 5522688   (26214400)
// yb    bf16 [32][256][1600]@ 31737088  (26214400)   total ~58 MB

// ---------------- pre 1: BN folds + adjacency normalize ----------------
__global__ __launch_bounds__(256) void k_pre(
    fp A, fp W, fp b, fp g0, fp b0, fp cw, fp cb, fp g2, fp b2,
    float* normA, float* Weff, float* beff, float* cbe, unsigned short* cwetb)
{
  int gid = blockIdx.x * 256 + threadIdx.x;
  const float inv_s = rsqrtf(1.0f + 1e-5f);

  if (gid < 16800) {                      // normA[k][g][v][w pad28]
    int k  = gid / 5600;
    int r  = gid % 5600;
    int g  = r / 700;
    int r2 = r % 700;
    int v  = r2 / 28, w = r2 % 28;
    float val = 0.f;
    if (w < 25) {
      float s = 0.f;
      for (int vv = 0; vv < 25; vv++) s += A[((k*8+g)*25+vv)*25 + w];
      val = A[((k*8+g)*25+v)*25 + w] / (s + 0.001f);
    }
    normA[gid] = val;
    return;
  }
  gid -= 16800;
  if (gid < 12288) {                      // Weff[cin][192]
    int d = gid % 192;
    Weff[gid] = W[gid] * (g0[d] * inv_s);
    return;
  }
  gid -= 12288;
  if (gid < 192) {                        // beff
    beff[gid] = b[gid] * (g0[gid] * inv_s) + b0[gid];
    return;
  }
  gid -= 192;
  if (gid < 64) {                         // cbe
    cbe[gid] = cb[gid] * (g2[gid] * inv_s) + b2[gid];
    return;
  }
  gid -= 64;
  if (gid < 36864) {                      // cwetb[o][j][i] bf16
    int o = gid / 576, r = gid % 576;
    int j = r / 64, i = r % 64;
    cwetb[gid] = f2us(cw[(o*64+i)*9 + j] * (g2[o] * inv_s));
  }
}

// ---------------- pre 2: combined GCN operator U (+identity) + biasU --------
__global__ __launch_bounds__(256) void k_pre2(
    const float* Weff, const float* beff, const float* normA, fp g1, fp b1,
    unsigned short* U, float* biasU)
{
  const float inv_s = rsqrtf(1.0f + 1e-5f);
  long long gid = (long long)blockIdx.x * 256 + threadIdx.x;
  const long long NU = 1664LL * 1600;
  if (gid < NU) {
    int m = (int)(gid / 1600), k = (int)(gid % 1600);
    unsigned short val = 0;
    if (m < 1600) {
      int c = m & 63, w = m >> 6;
      int cin = k / 25, vv = k % 25;
      float s1 = g1[c] * inv_s;
      float acc = 0.f;
      #pragma unroll
      for (int kk = 0; kk < 3; kk++)
        acc += Weff[cin*192 + kk*64 + c] * normA[((kk*8 + (c&7))*25 + vv)*28 + w];
      acc = acc * s1;
      if (cin == c && vv == w) acc += 1.0f;   // residual folded into diagonal
      val = f2us(acc);
    }
    U[gid] = val;
    return;
  }
  int m = (int)(gid - NU);
  if (m < 1600) {
    int c = m & 63, w = m >> 6;
    float s1 = g1[c] * inv_s;
    float acc = 0.f;
    for (int kk = 0; kk < 3; kk++) {
      float be = beff[kk*64 + c];
      for (int v = 0; v < 25; v++)
        acc += be * normA[((kk*8 + (c&7))*25 + v)*28 + w];
    }
    biasU[m] = acc * s1 + b1[c];
  }
}

// ---------------- transpose x -> bf16 [n][t][cin*25+v] ----------------
__global__ __launch_bounds__(256) void k_xt(fp x, unsigned short* xb)
{
  int gid = blockIdx.x * 256 + threadIdx.x;       // 8192*800 threads
  int nt = gid / 800, r = gid - nt*800;
  int n = nt >> 8, t = nt & 255;
  int q = r * 2;
  int c0 = q / 25, v0 = q - c0*25;
  int q1 = q + 1;
  int c1 = q1 / 25, v1 = q1 - c1*25;
  float f0 = x[((n*64 + c0)*256 + t)*25 + v0];
  float f1 = x[((n*64 + c1)*256 + t)*25 + v1];
  ushort2 pk;
  pk.x = f2us(f0); pk.y = f2us(f1);
  *(ushort2*)(xb + (long long)nt*1600 + q) = pk;
}

// ---------------- GCN as one MFMA GEMM, single-barrier dbuf pipeline --------
// yb[n][t][m] = relu( sum_k U[m][k]*xb[n][t][k] + biasU[m] )   (residual in U)
// Per iteration: barrier (drains chunk kc's DMA, issued one full compute phase
// earlier) -> issue DMA for chunk kc+1 into the other buffer -> compute chunk
// kc. The compiler's forced vmcnt(0)-before-barrier now waits on old loads.
// XOR-swizzled k-columns keep DMA deposits contiguous and ds_read_b128 2-way.
__global__ __launch_bounds__(256) void k_gemm(
    const unsigned short* U, const unsigned short* xb, const float* biasU,
    unsigned short* yb)
{
  int bm = blockIdx.x / 64, bn = blockIdx.x % 64;
  int n = bn >> 1, t0 = (bn & 1) * 128;
  int tid = threadIdx.x, lane = tid & 63, wid = tid >> 6;
  int l15 = lane & 15, grp = lane >> 4;
  int m0w = (wid & 1) * 64, c0w = (wid >> 1) * 64;

  __shared__ __align__(16) unsigned short As[2][128*64];
  __shared__ __align__(16) unsigned short Bs[2][128*64];

  // staging geometry: e = it*256+tid, row=e>>3, li=e&7 (lane-contiguous LDS)
  const unsigned short* gA[4];
  const unsigned short* gB[4];
  int loff[4];
  #pragma unroll
  for (int it = 0; it < 4; it++) {
    int e = it*256 + tid;
    int row = e >> 3, li = e & 7;
    int kcol = (li ^ (row & 7)) * 8;       // XOR swizzle on global source side
    gA[it] = U  + (long long)(bm*128 + row)*1600 + kcol;
    gB[it] = xb + (long long)(n*256 + t0 + row)*1600 + kcol;
    loff[it] = e*8;
  }

  // prologue: chunk 0 -> buffer 0
  #pragma unroll
  for (int it = 0; it < 4; it++) {
    gload_lds16(gA[it], &As[0][loff[it]]);
    gload_lds16(gB[it], &Bs[0][loff[it]]);
  }

  floatx4 acc[4][4];
  #pragma unroll
  for (int i = 0; i < 4; i++)
    #pragma unroll
    for (int j = 0; j < 4; j++) acc[i][j] = (floatx4){0.f,0.f,0.f,0.f};

  for (int kc = 0; kc < 25; kc++) {
    int cur = kc & 1;
    __syncthreads();            // drains chunk kc DMA + prev buf reads
    if (kc < 24) {              // prefetch chunk kc+1 into other buffer
      #pragma unroll
      for (int it = 0; it < 4; it++) {
        gload_lds16(gA[it] + (kc+1)*64, &As[cur^1][loff[it]]);
        gload_lds16(gB[it] + (kc+1)*64, &Bs[cur^1][loff[it]]);
      }
    }
    #pragma unroll
    for (int ks = 0; ks < 2; ks++) {
      int colk = ((ks*4 + grp) ^ (l15 & 7)) * 8;   // un-swizzle at read
      short8 af[4], bf[4];
      #pragma unroll
      for (int i = 0; i < 4; i++)
        af[i] = *(const short8*)(&As[cur][(m0w + i*16 + l15)*64 + colk]);
      #pragma unroll
      for (int j = 0; j < 4; j++)
        bf[j] = *(const short8*)(&Bs[cur][(c0w + j*16 + l15)*64 + colk]);
      #pragma unroll
      for (int i = 0; i < 4; i++)
        #pragma unroll
        for (int j = 0; j < 4; j++)
          acc[i][j] = __builtin_amdgcn_mfma_f32_16x16x32_bf16(af[i], bf[j], acc[i][j], 0, 0, 0);
    }
  }

  // epilogue: bias + relu -> yb bf16 (residual already inside U)
  #pragma unroll
  for (int i = 0; i < 4; i++) {
    int mbase = bm*128 + m0w + i*16 + grp*4;
    if (mbase >= 1600) continue;
    float4 bu = *(const float4*)(biasU + mbase);
    #pragma unroll
    for (int j = 0; j < 4; j++) {
      int col = c0w + j*16 + l15;
      int t = t0 + col;
      ushort4 pk;
      pk.x = f2us(fmaxf(acc[i][j][0] + bu.x, 0.f));
      pk.y = f2us(fmaxf(acc[i][j][1] + bu.y, 0.f));
      pk.z = f2us(fmaxf(acc[i][j][2] + bu.z, 0.f));
      pk.w = f2us(fmaxf(acc[i][j][3] + bu.w, 0.f));
      *(ushort4*)(yb + (long long)(n*256 + t)*1600 + mbase) = pk;
    }
  }
}

// ---------------- TCN as MFMA with im2col via LDS offsets ----------------
__global__ __launch_bounds__(256) void k_tcn(
    const unsigned short* yb, const unsigned short* cwetb, const float* cbe,
    fp x, float* out)
{
  int n = blockIdx.x >> 5, tb = blockIdx.x & 31, t0 = tb*8;
  int tid = threadIdx.x, lane = tid & 63, wid = tid >> 6;
  int l15 = lane & 15, grp = lane >> 4;
  __shared__ __align__(16) unsigned short ys[425*72];  // [17 t][25 v][72 i-pad]

  for (int e = tid; e < 3400; e += 256) {
    int row = e >> 3, li = e & 7;
    int rt = row / 25, v = row - rt*25;
    int tg = t0 - 4 + rt;
    uint4 val = {0u,0u,0u,0u};
    if (tg >= 0 && tg < 256)
      val = *(const uint4*)(yb + ((long long)(n*256 + tg)*1600 + v*64 + li*8));
    *(uint4*)(ys + row*72 + li*8) = val;
  }

  // A-frags: conv weights, o = o0+l15, k-dim = i
  int o0 = wid * 16;
  int o = o0 + l15;
  short8 af[9][2];
  #pragma unroll
  for (int j = 0; j < 9; j++) {
    af[j][0] = *(const short8*)(cwetb + ((o*9 + j)*64 + grp*8));
    af[j][1] = *(const short8*)(cwetb + ((o*9 + j)*64 + 32 + grp*8));
  }
  float4 cb4 = *(const float4*)(cbe + o0 + grp*4);
  __syncthreads();

  for (int tile = 0; tile < 13; tile++) {
    int colb = tile*16 + l15;
    int bbase = colb*72 + grp*8;
    floatx4 acc = (floatx4){0.f,0.f,0.f,0.f};
    #pragma unroll
    for (int j = 0; j < 9; j++) {
      short8 b0 = *(const short8*)(ys + bbase + j*1800);
      short8 b1 = *(const short8*)(ys + bbase + j*1800 + 32);
      acc = __builtin_amdgcn_mfma_f32_16x16x32_bf16(af[j][0], b0, acc, 0, 0, 0);
      acc = __builtin_amdgcn_mfma_f32_16x16x32_bf16(af[j][1], b1, acc, 0, 0, 0);
    }
    if (colb < 200) {
      int tt = colb / 25, v = colb - tt*25, t = t0 + tt;
      #pragma unroll
      for (int r = 0; r < 4; r++) {
        int oo = o0 + grp*4 + r;
        float val = acc[r] + ((const float*)&cb4)[r]
                  + x[((n*64 + oo)*256 + t)*25 + v];
        out[((n*64 + oo)*256 + t)*25 + v] = fmaxf(val, 0.f);
      }
    }
  }
}

extern "C" void kernel_launch(void* const* d_in, const int* in_sizes, int n_in,
                              void* d_out, int out_size, void* d_ws, size_t ws_size,
                              hipStream_t stream)
{
  fp x  = (fp)d_in[0];
  fp A  = (fp)d_in[1];
  fp W  = (fp)d_in[2];
  fp b  = (fp)d_in[3];
  fp g0 = (fp)d_in[4];
  fp b0 = (fp)d_in[5];
  fp g1 = (fp)d_in[6];
  fp b1 = (fp)d_in[7];
  fp cw = (fp)d_in[8];
  fp cb = (fp)d_in[9];
  fp g2 = (fp)d_in[10];
  fp b2 = (fp)d_in[11];
  // d_in[12] = keep_prob == 1 -> DropBlocks identity.

  char* ws = (char*)d_ws;
  float*          normA = (float*)(ws + 0);
  float*          Weff  = (float*)(ws + 67584);
  float*          beff  = (float*)(ws + 116736);
  float*          cbe   = (float*)(ws + 117504);
  unsigned short* cwetb = (unsigned short*)(ws + 117760);
  float*          biasU = (float*)(ws + 191488);
  unsigned short* U     = (unsigned short*)(ws + 197888);
  unsigned short* xb    = (unsigned short*)(ws + 5522688);
  unsigned short* yb    = (unsigned short*)(ws + 31737088);

  k_pre<<<259, 256, 0, stream>>>(A, W, b, g0, b0, cw, cb, g2, b2,
                                 normA, Weff, beff, cbe, cwetb);
  k_pre2<<<10407, 256, 0, stream>>>(Weff, beff, normA, g1, b1, U, biasU);
  k_xt<<<25600, 256, 0, stream>>>(x, xb);
  k_gemm<<<832, 256, 0, stream>>>(U, xb, biasU, yb);
  k_tcn<<<1024, 256, 0, stream>>>(yb, cwetb, cbe, x, (float*)d_out);
}

// Round 6
// 259.251 us; speedup vs baseline: 1.0142x; 1.0142x over previous
//
#include <hip/hip_runtime.h>
#include <hip/hip_bf16.h>
#include <stdint.h>

// Shapes: N=32, CIN=COUT=64, T=256, V=25, K3=3, G=8
// GCN folded to one GEMM: M=1600 (m=w*64+c), K=1600 (k=cin*25+v), N=8192 (n,t)
//   residual (+x) folded into U's diagonal: U[w*64+c][c*25+w] += 1
// TCN: MFMA im2col GEMM: M=64 (o), K=576 (i,j), N=204800 (n,t,v)

typedef const float* fp;
typedef __attribute__((ext_vector_type(8))) short short8;   // 8 bf16 (4 VGPRs)
typedef __attribute__((ext_vector_type(4))) float floatx4;  // MFMA acc

__device__ __forceinline__ float us2f(unsigned int u){
  union { unsigned int i; float f; } c; c.i = u << 16; return c.f;
}
__device__ __forceinline__ unsigned short f2us(float f){
  __hip_bfloat16 h = __float2bfloat16(f);
  return *reinterpret_cast<unsigned short*>(&h);
}
__device__ __forceinline__ void gload_lds16(const void* g, void* l){
  __builtin_amdgcn_global_load_lds(
      (const __attribute__((address_space(1))) void*)g,
      (__attribute__((address_space(3))) void*)l, 16, 0, 0);
}

// ---------------- workspace layout (bytes) ----------------
// normA fp32 [3][8][25][28] @ 0         (67200)
// Weff  fp32 [64][192]      @ 67584     (49152)
// beff  fp32 [192]          @ 116736    (768)
// cbe   fp32 [64]           @ 117504    (256)
// cwetb bf16 [64][9][64]    @ 117760    (73728)
// biasU fp32 [1600]         @ 191488    (6400)
// U     bf16 [1664][1600]   @ 197888    (5324800)
// xb    bf16 [32][256][1600]@ 5522688   (26214400)
// yb    bf16 [32][256][1600]@ 31737088  (26214400)   total ~58 MB

// ---------------- pre 1: BN folds + adjacency normalize ----------------
__global__ __launch_bounds__(256) void k_pre(
    fp A, fp W, fp b, fp g0, fp b0, fp cw, fp cb, fp g2, fp b2,
    float* normA, float* Weff, float* beff, float* cbe, unsigned short* cwetb)
{
  int gid = blockIdx.x * 256 + threadIdx.x;
  const float inv_s = rsqrtf(1.0f + 1e-5f);

  if (gid < 16800) {                      // normA[k][g][v][w pad28]
    int k  = gid / 5600;
    int r  = gid % 5600;
    int g  = r / 700;
    int r2 = r % 700;
    int v  = r2 / 28, w = r2 % 28;
    float val = 0.f;
    if (w < 25) {
      float s = 0.f;
      for (int vv = 0; vv < 25; vv++) s += A[((k*8+g)*25+vv)*25 + w];
      val = A[((k*8+g)*25+v)*25 + w] / (s + 0.001f);
    }
    normA[gid] = val;
    return;
  }
  gid -= 16800;
  if (gid < 12288) {                      // Weff[cin][192]
    int d = gid % 192;
    Weff[gid] = W[gid] * (g0[d] * inv_s);
    return;
  }
  gid -= 12288;
  if (gid < 192) {                        // beff
    beff[gid] = b[gid] * (g0[gid] * inv_s) + b0[gid];
    return;
  }
  gid -= 192;
  if (gid < 64) {                         // cbe
    cbe[gid] = cb[gid] * (g2[gid] * inv_s) + b2[gid];
    return;
  }
  gid -= 64;
  if (gid < 36864) {                      // cwetb[o][j][i] bf16
    int o = gid / 576, r = gid % 576;
    int j = r / 64, i = r % 64;
    cwetb[gid] = f2us(cw[(o*64+i)*9 + j] * (g2[o] * inv_s));
  }
}

// ---------------- pre 2: U rows via LDS-cached factors ----------------
// block = one U row m. nAL (75 floats) + WeffL (192 floats) cached once,
// then 1600 coalesced bf16 stores with 3 FMAs each.
__global__ __launch_bounds__(256) void k_pre2(
    const float* Weff, const float* beff, const float* normA, fp g1, fp b1,
    unsigned short* U, float* biasU)
{
  int m = blockIdx.x;                     // 1664 blocks
  int tid = threadIdx.x;
  if (m >= 1600) {                        // zero-pad rows (uniform per block)
    for (int k = tid; k < 1600; k += 256) U[(long long)m*1600 + k] = 0;
    return;
  }
  int c = m & 63, w = m >> 6, g = c & 7;
  __shared__ float nAL[75];               // [kk][vv] = normA[kk,g,vv,w]
  __shared__ float WeffL[192];            // [kk][cin]
  if (tid < 75) {
    int kk = tid / 25, vv = tid % 25;
    nAL[tid] = normA[((kk*8 + g)*25 + vv)*28 + w];
  }
  if (tid < 192) {
    int kk = tid >> 6, cin = tid & 63;
    WeffL[tid] = Weff[cin*192 + kk*64 + c];
  }
  __syncthreads();
  float s1 = g1[c] * rsqrtf(1.0f + 1e-5f);
  for (int k = tid; k < 1600; k += 256) {
    int cin = k / 25, vv = k - cin*25;
    float acc = WeffL[cin]       * nAL[vv]
              + WeffL[64 + cin]  * nAL[25 + vv]
              + WeffL[128 + cin] * nAL[50 + vv];
    acc *= s1;
    if (cin == c && vv == w) acc += 1.0f;  // residual folded into diagonal
    U[(long long)m*1600 + k] = f2us(acc);
  }
  if (tid == 0) {
    float acc = 0.f;
    for (int kk = 0; kk < 3; kk++) {
      float be = beff[kk*64 + c];
      for (int v = 0; v < 25; v++) acc += be * nAL[kk*25 + v];
    }
    biasU[m] = acc * s1 + b1[c];
  }
}

// ---------------- transpose x -> bf16 [n][t][cin*25+v] (LDS, coalesced) ----
__global__ __launch_bounds__(256) void k_xt(fp x, unsigned short* xb)
{
  int n = blockIdx.x >> 5, tb = blockIdx.x & 31, t0 = tb*8, tid = threadIdx.x;
  __shared__ unsigned short xs[64*8*26];
  for (int e = tid; e < 12800; e += 256) {
    int c = e / 200, r = e - c*200, tt = r / 25, v = r - tt*25;
    xs[(c*8 + tt)*26 + v] = f2us(x[((n*64 + c)*256 + t0 + tt)*25 + v]);
  }
  __syncthreads();
  for (int e = tid; e < 12800; e += 256) {
    int tt = e / 1600, q = e - tt*1600, c = q / 25, v = q - c*25;
    xb[(n*256 + t0 + tt)*1600 + q] = xs[(c*8 + tt)*26 + v];
  }
}

// ---------------- GCN as one MFMA GEMM (m97 structure) ----------------
// yb[n][t][m] = relu( sum_k U[m][k]*xb[n][t][k] + biasU[m] )   (residual in U)
// Unpadded [128][64] LDS; k-columns XOR-swizzled on the global source side so
// DMA deposits stay contiguous and fragment ds_read_b128s are conflict-free.
__global__ __launch_bounds__(256) void k_gemm(
    const unsigned short* U, const unsigned short* xb, const float* biasU,
    unsigned short* yb)
{
  int bm = blockIdx.x / 64, bn = blockIdx.x % 64;
  int n = bn >> 1, t0 = (bn & 1) * 128;
  int tid = threadIdx.x, lane = tid & 63, wid = tid >> 6;
  int l15 = lane & 15, grp = lane >> 4;
  int m0w = (wid & 1) * 64, c0w = (wid >> 1) * 64;

  __shared__ __align__(16) unsigned short As[128*64];
  __shared__ __align__(16) unsigned short Bs[128*64];

  const unsigned short* gA[4];
  const unsigned short* gB[4];
  unsigned short* lA[4];
  unsigned short* lB[4];
  #pragma unroll
  for (int it = 0; it < 4; it++) {
    int e = it*256 + tid;
    int row = e >> 3, li = e & 7;
    int kcol = (li ^ (row & 7)) * 8;       // XOR swizzle on global source side
    gA[it] = U  + (long long)(bm*128 + row)*1600 + kcol;
    gB[it] = xb + (long long)(n*256 + t0 + row)*1600 + kcol;
    lA[it] = As + e*8;
    lB[it] = Bs + e*8;
  }

  floatx4 acc[4][4];
  #pragma unroll
  for (int i = 0; i < 4; i++)
    #pragma unroll
    for (int j = 0; j < 4; j++) acc[i][j] = (floatx4){0.f,0.f,0.f,0.f};

  for (int kc = 0; kc < 25; kc++) {
    #pragma unroll
    for (int it = 0; it < 4; it++) {
      gload_lds16(gA[it] + kc*64, lA[it]);
      gload_lds16(gB[it] + kc*64, lB[it]);
    }
    __syncthreads();
    #pragma unroll
    for (int ks = 0; ks < 2; ks++) {
      int colk = ((ks*4 + grp) ^ (l15 & 7)) * 8;   // un-swizzle at read
      short8 af[4], bf[4];
      #pragma unroll
      for (int i = 0; i < 4; i++) af[i] = *(const short8*)(As + (m0w + i*16 + l15)*64 + colk);
      #pragma unroll
      for (int j = 0; j < 4; j++) bf[j] = *(const short8*)(Bs + (c0w + j*16 + l15)*64 + colk);
      #pragma unroll
      for (int i = 0; i < 4; i++)
        #pragma unroll
        for (int j = 0; j < 4; j++)
          acc[i][j] = __builtin_amdgcn_mfma_f32_16x16x32_bf16(af[i], bf[j], acc[i][j], 0, 0, 0);
    }
    __syncthreads();
  }

  #pragma unroll
  for (int i = 0; i < 4; i++) {
    int mbase = bm*128 + m0w + i*16 + grp*4;
    if (mbase >= 1600) continue;
    float4 bu = *(const float4*)(biasU + mbase);
    #pragma unroll
    for (int j = 0; j < 4; j++) {
      int col = c0w + j*16 + l15;
      int t = t0 + col;
      ushort4 pk;
      pk.x = f2us(fmaxf(acc[i][j][0] + bu.x, 0.f));
      pk.y = f2us(fmaxf(acc[i][j][1] + bu.y, 0.f));
      pk.z = f2us(fmaxf(acc[i][j][2] + bu.z, 0.f));
      pk.w = f2us(fmaxf(acc[i][j][3] + bu.w, 0.f));
      *(ushort4*)(yb + (long long)(n*256 + t)*1600 + mbase) = pk;
    }
  }
}

// ---------------- TCN as MFMA, conflict-free swizzled LDS ----------------
// ys rows = (t,v) cols of the im2col window, 64 i's per row, i-group columns
// XOR-swizzled by (row&7) — same proven 0-conflict pattern as k_gemm.
__global__ __launch_bounds__(256) void k_tcn(
    const unsigned short* yb, const unsigned short* cwetb, const float* cbe,
    fp x, float* out)
{
  int n = blockIdx.x >> 5, tb = blockIdx.x & 31, t0 = tb*8;
  int tid = threadIdx.x, lane = tid & 63, wid = tid >> 6;
  int l15 = lane & 15, grp = lane >> 4;
  __shared__ __align__(16) unsigned short ys[425*64];  // [17t*25v][64 i] swizzled

  for (int e = tid; e < 3400; e += 256) {
    int row = e >> 3, li = e & 7;
    int rt = row / 25, v = row - rt*25;
    int tg = t0 - 4 + rt;
    int sli = li ^ (row & 7);             // fetch swizzled i-group
    uint4 val = {0u,0u,0u,0u};
    if (tg >= 0 && tg < 256)
      val = *(const uint4*)(yb + ((long long)(n*256 + tg)*1600 + v*64 + sli*8));
    *(uint4*)(ys + e*8) = val;            // linear LDS deposit
  }

  // A-frags: conv weights in registers, o = o0+l15, k-dim = i
  int o0 = wid * 16;
  int o = o0 + l15;
  short8 af[9][2];
  #pragma unroll
  for (int j = 0; j < 9; j++) {
    af[j][0] = *(const short8*)(cwetb + ((o*9 + j)*64 + grp*8));
    af[j][1] = *(const short8*)(cwetb + ((o*9 + j)*64 + 32 + grp*8));
  }
  float4 cb4 = *(const float4*)(cbe + o0 + grp*4);
  __syncthreads();

  for (int tile = 0; tile < 13; tile++) {
    int colb = tile*16 + l15;
    floatx4 acc = (floatx4){0.f,0.f,0.f,0.f};
    #pragma unroll
    for (int j = 0; j < 9; j++) {
      int row = colb + 25*j;
      int r7 = row & 7;
      const unsigned short* rb = ys + row*64;
      short8 b0 = *(const short8*)(rb + ((grp     ^ r7))*8);   // kg=grp
      short8 b1 = *(const short8*)(rb + (((4+grp) ^ r7))*8);   // kg=4+grp
      acc = __builtin_amdgcn_mfma_f32_16x16x32_bf16(af[j][0], b0, acc, 0, 0, 0);
      acc = __builtin_amdgcn_mfma_f32_16x16x32_bf16(af[j][1], b1, acc, 0, 0, 0);
    }
    if (colb < 200) {
      int tt = colb / 25, v = colb - tt*25, t = t0 + tt;
      #pragma unroll
      for (int r = 0; r < 4; r++) {
        int oo = o0 + grp*4 + r;
        float val = acc[r] + ((const float*)&cb4)[r]
                  + x[((n*64 + oo)*256 + t)*25 + v];
        out[((n*64 + oo)*256 + t)*25 + v] = fmaxf(val, 0.f);
      }
    }
  }
}

extern "C" void kernel_launch(void* const* d_in, const int* in_sizes, int n_in,
                              void* d_out, int out_size, void* d_ws, size_t ws_size,
                              hipStream_t stream)
{
  fp x  = (fp)d_in[0];
  fp A  = (fp)d_in[1];
  fp W  = (fp)d_in[2];
  fp b  = (fp)d_in[3];
  fp g0 = (fp)d_in[4];
  fp b0 = (fp)d_in[5];
  fp g1 = (fp)d_in[6];
  fp b1 = (fp)d_in[7];
  fp cw = (fp)d_in[8];
  fp cb = (fp)d_in[9];
  fp g2 = (fp)d_in[10];
  fp b2 = (fp)d_in[11];
  // d_in[12] = keep_prob == 1 -> DropBlocks identity.

  char* ws = (char*)d_ws;
  float*          normA = (float*)(ws + 0);
  float*          Weff  = (float*)(ws + 67584);
  float*          beff  = (float*)(ws + 116736);
  float*          cbe   = (float*)(ws + 117504);
  unsigned short* cwetb = (unsigned short*)(ws + 117760);
  float*          biasU = (float*)(ws + 191488);
  unsigned short* U     = (unsigned short*)(ws + 197888);
  unsigned short* xb    = (unsigned short*)(ws + 5522688);
  unsigned short* yb    = (unsigned short*)(ws + 31737088);

  k_pre<<<259, 256, 0, stream>>>(A, W, b, g0, b0, cw, cb, g2, b2,
                                 normA, Weff, beff, cbe, cwetb);
  k_pre2<<<1664, 256, 0, stream>>>(Weff, beff, normA, g1, b1, U, biasU);
  k_xt<<<1024, 256, 0, stream>>>(x, xb);
  k_gemm<<<832, 256, 0, stream>>>(U, xb, biasU, yb);
  k_tcn<<<1024, 256, 0, stream>>>(yb, cwetb, cbe, x, (float*)d_out);
}

// Round 7
// 240.708 us; speedup vs baseline: 1.0923x; 1.0770x over previous
//
#include <hip/hip_runtime.h>
#include <hip/hip_bf16.h>
#include <stdint.h>

// Shapes: N=32, CIN=COUT=64, T=256, V=25, K3=3, G=8
// GCN folded to one GEMM: M=1600 (m=w*64+c), K=1600 (k=cin*25+v), N=8192 (n,t)
//   residual (+x) folded into U's diagonal: U[w*64+c][c*25+w] += 1
// k_gemm v2: 256m x 128n tiles, private-A wave strips (traffic-bound fix)
// TCN: MFMA im2col GEMM: M=64 (o), K=576 (i,j), N=204800 (n,t,v)

typedef const float* fp;
typedef __attribute__((ext_vector_type(8))) short short8;   // 8 bf16 (4 VGPRs)
typedef __attribute__((ext_vector_type(4))) float floatx4;  // MFMA acc

__device__ __forceinline__ float us2f(unsigned int u){
  union { unsigned int i; float f; } c; c.i = u << 16; return c.f;
}
__device__ __forceinline__ unsigned short f2us(float f){
  __hip_bfloat16 h = __float2bfloat16(f);
  return *reinterpret_cast<unsigned short*>(&h);
}
__device__ __forceinline__ void gload_lds16(const void* g, void* l){
  __builtin_amdgcn_global_load_lds(
      (const __attribute__((address_space(1))) void*)g,
      (__attribute__((address_space(3))) void*)l, 16, 0, 0);
}

// ---------------- workspace layout (bytes) ----------------
// normA fp32 [3][8][25][28] @ 0         (67200)
// Weff  fp32 [64][192]      @ 67584     (49152)
// beff  fp32 [192]          @ 116736    (768)
// cbe   fp32 [64]           @ 117504    (256)
// cwetb bf16 [64][9][64]    @ 117760    (73728)
// biasU fp32 [1600]         @ 191488    (6400)
// U     bf16 [1792][1600]   @ 197888    (5734400)
// xb    bf16 [32][256][1600]@ 5932288   (26214400)
// yb    bf16 [32][256][1600]@ 32146688  (26214400)   total ~58.4 MB

// ---------------- pre 1: BN folds + adjacency normalize ----------------
__global__ __launch_bounds__(256) void k_pre(
    fp A, fp W, fp b, fp g0, fp b0, fp cw, fp cb, fp g2, fp b2,
    float* normA, float* Weff, float* beff, float* cbe, unsigned short* cwetb)
{
  int gid = blockIdx.x * 256 + threadIdx.x;
  const float inv_s = rsqrtf(1.0f + 1e-5f);

  if (gid < 16800) {                      // normA[k][g][v][w pad28]
    int k  = gid / 5600;
    int r  = gid % 5600;
    int g  = r / 700;
    int r2 = r % 700;
    int v  = r2 / 28, w = r2 % 28;
    float val = 0.f;
    if (w < 25) {
      float s = 0.f;
      for (int vv = 0; vv < 25; vv++) s += A[((k*8+g)*25+vv)*25 + w];
      val = A[((k*8+g)*25+v)*25 + w] / (s + 0.001f);
    }
    normA[gid] = val;
    return;
  }
  gid -= 16800;
  if (gid < 12288) {                      // Weff[cin][192]
    int d = gid % 192;
    Weff[gid] = W[gid] * (g0[d] * inv_s);
    return;
  }
  gid -= 12288;
  if (gid < 192) {                        // beff
    beff[gid] = b[gid] * (g0[gid] * inv_s) + b0[gid];
    return;
  }
  gid -= 192;
  if (gid < 64) {                         // cbe
    cbe[gid] = cb[gid] * (g2[gid] * inv_s) + b2[gid];
    return;
  }
  gid -= 64;
  if (gid < 36864) {                      // cwetb[o][j][i] bf16
    int o = gid / 576, r = gid % 576;
    int j = r / 64, i = r % 64;
    cwetb[gid] = f2us(cw[(o*64+i)*9 + j] * (g2[o] * inv_s));
  }
}

// ---------------- pre 2: U rows via LDS-cached factors ----------------
__global__ __launch_bounds__(256) void k_pre2(
    const float* Weff, const float* beff, const float* normA, fp g1, fp b1,
    unsigned short* U, float* biasU)
{
  int m = blockIdx.x;                     // 1792 blocks
  int tid = threadIdx.x;
  if (m >= 1600) {                        // zero-pad rows (uniform per block)
    for (int k = tid; k < 1600; k += 256) U[(long long)m*1600 + k] = 0;
    return;
  }
  int c = m & 63, w = m >> 6, g = c & 7;
  __shared__ float nAL[75];               // [kk][vv] = normA[kk,g,vv,w]
  __shared__ float WeffL[192];            // [kk][cin]
  if (tid < 75) {
    int kk = tid / 25, vv = tid % 25;
    nAL[tid] = normA[((kk*8 + g)*25 + vv)*28 + w];
  }
  if (tid < 192) {
    int kk = tid >> 6, cin = tid & 63;
    WeffL[tid] = Weff[cin*192 + kk*64 + c];
  }
  __syncthreads();
  float s1 = g1[c] * rsqrtf(1.0f + 1e-5f);
  for (int k = tid; k < 1600; k += 256) {
    int cin = k / 25, vv = k - cin*25;
    float acc = WeffL[cin]       * nAL[vv]
              + WeffL[64 + cin]  * nAL[25 + vv]
              + WeffL[128 + cin] * nAL[50 + vv];
    acc *= s1;
    if (cin == c && vv == w) acc += 1.0f;  // residual folded into diagonal
    U[(long long)m*1600 + k] = f2us(acc);
  }
  if (tid == 0) {
    float acc = 0.f;
    for (int kk = 0; kk < 3; kk++) {
      float be = beff[kk*64 + c];
      for (int v = 0; v < 25; v++) acc += be * nAL[kk*25 + v];
    }
    biasU[m] = acc * s1 + b1[c];
  }
}

// ---------------- transpose x -> bf16 [n][t][cin*25+v] (LDS, coalesced) ----
__global__ __launch_bounds__(256) void k_xt(fp x, unsigned short* xb)
{
  int n = blockIdx.x >> 5, tb = blockIdx.x & 31, t0 = tb*8, tid = threadIdx.x;
  __shared__ unsigned short xs[64*8*26];
  for (int e = tid; e < 12800; e += 256) {
    int c = e / 200, r = e - c*200, tt = r / 25, v = r - tt*25;
    xs[(c*8 + tt)*26 + v] = f2us(x[((n*64 + c)*256 + t0 + tt)*25 + v]);
  }
  __syncthreads();
  for (int e = tid; e < 12800; e += 256) {
    int tt = e / 1600, q = e - tt*1600, c = q / 25, v = q - c*25;
    xb[(n*256 + t0 + tt)*1600 + q] = xs[(c*8 + tt)*26 + v];
  }
}

// ---------------- GCN GEMM v2: 256m x 128n, private-A wave strips ----------
// yb[n][t][m] = relu( sum_k U[m][k]*xb[n][t][k] + biasU[m] )   (residual in U)
// Wave w owns m-strip [w*64, w*64+64) x all 128 n: A-frags read once,
// acc[4][8]. 48 KB LDS single-buffer. XOR-swizzled k-cols (proven 0-conflict).
__global__ __launch_bounds__(256, 2) void k_gemm(
    const unsigned short* U, const unsigned short* xb, const float* biasU,
    unsigned short* yb)
{
  int bm = blockIdx.x >> 6, bn = blockIdx.x & 63;   // 7 x 64
  int n = bn >> 1, t0 = (bn & 1) * 128;
  int tid = threadIdx.x, lane = tid & 63, wid = tid >> 6;
  int l15 = lane & 15, grp = lane >> 4;

  __shared__ __align__(16) unsigned short As[256*64];  // 32 KB
  __shared__ __align__(16) unsigned short Bs[128*64];  // 16 KB

  // staging: A 8 slots/thread, B 4 slots/thread; e = it*256+tid
  const unsigned short* gA[8];
  const unsigned short* gB[4];
  unsigned short* lA[8];
  unsigned short* lB[4];
  #pragma unroll
  for (int it = 0; it < 8; it++) {
    int e = it*256 + tid;
    int row = e >> 3, li = e & 7;
    int kcol = (li ^ (row & 7)) * 8;       // XOR swizzle on global source side
    gA[it] = U + (long long)(bm*256 + row)*1600 + kcol;
    lA[it] = As + e*8;
  }
  #pragma unroll
  for (int it = 0; it < 4; it++) {
    int e = it*256 + tid;
    int row = e >> 3, li = e & 7;
    int kcol = (li ^ (row & 7)) * 8;
    gB[it] = xb + (long long)(n*256 + t0 + row)*1600 + kcol;
    lB[it] = Bs + e*8;
  }

  floatx4 acc[4][8];
  #pragma unroll
  for (int i = 0; i < 4; i++)
    #pragma unroll
    for (int j = 0; j < 8; j++) acc[i][j] = (floatx4){0.f,0.f,0.f,0.f};

  for (int kc = 0; kc < 25; kc++) {
    #pragma unroll
    for (int it = 0; it < 8; it++) gload_lds16(gA[it] + kc*64, lA[it]);
    #pragma unroll
    for (int it = 0; it < 4; it++) gload_lds16(gB[it] + kc*64, lB[it]);
    __syncthreads();
    #pragma unroll
    for (int ks = 0; ks < 2; ks++) {
      int colk = ((ks*4 + grp) ^ (l15 & 7)) * 8;   // un-swizzle at read
      short8 af[4], bf[8];
      #pragma unroll
      for (int i = 0; i < 4; i++)
        af[i] = *(const short8*)(As + (wid*64 + i*16 + l15)*64 + colk);
      #pragma unroll
      for (int j = 0; j < 8; j++)
        bf[j] = *(const short8*)(Bs + (j*16 + l15)*64 + colk);
      #pragma unroll
      for (int i = 0; i < 4; i++)
        #pragma unroll
        for (int j = 0; j < 8; j++)
          acc[i][j] = __builtin_amdgcn_mfma_f32_16x16x32_bf16(af[i], bf[j], acc[i][j], 0, 0, 0);
    }
    __syncthreads();
  }

  // epilogue: bias + relu -> yb bf16 (residual already inside U)
  #pragma unroll
  for (int i = 0; i < 4; i++) {
    int mbase = bm*256 + wid*64 + i*16 + grp*4;
    if (mbase >= 1600) continue;
    float4 bu = *(const float4*)(biasU + mbase);
    #pragma unroll
    for (int j = 0; j < 8; j++) {
      int col = j*16 + l15;
      int t = t0 + col;
      ushort4 pk;
      pk.x = f2us(fmaxf(acc[i][j][0] + bu.x, 0.f));
      pk.y = f2us(fmaxf(acc[i][j][1] + bu.y, 0.f));
      pk.z = f2us(fmaxf(acc[i][j][2] + bu.z, 0.f));
      pk.w = f2us(fmaxf(acc[i][j][3] + bu.w, 0.f));
      *(ushort4*)(yb + (long long)(n*256 + t)*1600 + mbase) = pk;
    }
  }
}

// ---------------- TCN as MFMA, conflict-free swizzled LDS ----------------
__global__ __launch_bounds__(256) void k_tcn(
    const unsigned short* yb, const unsigned short* cwetb, const float* cbe,
    fp x, float* out)
{
  int n = blockIdx.x >> 5, tb = blockIdx.x & 31, t0 = tb*8;
  int tid = threadIdx.x, lane = tid & 63, wid = tid >> 6;
  int l15 = lane & 15, grp = lane >> 4;
  __shared__ __align__(16) unsigned short ys[425*64];  // [17t*25v][64 i] swizzled

  for (int e = tid; e < 3400; e += 256) {
    int row = e >> 3, li = e & 7;
    int rt = row / 25, v = row - rt*25;
    int tg = t0 - 4 + rt;
    int sli = li ^ (row & 7);             // fetch swizzled i-group
    uint4 val = {0u,0u,0u,0u};
    if (tg >= 0 && tg < 256)
      val = *(const uint4*)(yb + ((long long)(n*256 + tg)*1600 + v*64 + sli*8));
    *(uint4*)(ys + e*8) = val;            // linear LDS deposit
  }

  // A-frags: conv weights in registers, o = o0+l15, k-dim = i
  int o0 = wid * 16;
  int o = o0 + l15;
  short8 af[9][2];
  #pragma unroll
  for (int j = 0; j < 9; j++) {
    af[j][0] = *(const short8*)(cwetb + ((o*9 + j)*64 + grp*8));
    af[j][1] = *(const short8*)(cwetb + ((o*9 + j)*64 + 32 + grp*8));
  }
  float4 cb4 = *(const float4*)(cbe + o0 + grp*4);
  __syncthreads();

  for (int tile = 0; tile < 13; tile++) {
    int colb = tile*16 + l15;
    floatx4 acc = (floatx4){0.f,0.f,0.f,0.f};
    #pragma unroll
    for (int j = 0; j < 9; j++) {
      int row = colb + 25*j;
      int r7 = row & 7;
      const unsigned short* rb = ys + row*64;
      short8 b0 = *(const short8*)(rb + ((grp     ^ r7))*8);
      short8 b1 = *(const short8*)(rb + (((4+grp) ^ r7))*8);
      acc = __builtin_amdgcn_mfma_f32_16x16x32_bf16(af[j][0], b0, acc, 0, 0, 0);
      acc = __builtin_amdgcn_mfma_f32_16x16x32_bf16(af[j][1], b1, acc, 0, 0, 0);
    }
    if (colb < 200) {
      int tt = colb / 25, v = colb - tt*25, t = t0 + tt;
      #pragma unroll
      for (int r = 0; r < 4; r++) {
        int oo = o0 + grp*4 + r;
        float val = acc[r] + ((const float*)&cb4)[r]
                  + x[((n*64 + oo)*256 + t)*25 + v];
        out[((n*64 + oo)*256 + t)*25 + v] = fmaxf(val, 0.f);
      }
    }
  }
}

extern "C" void kernel_launch(void* const* d_in, const int* in_sizes, int n_in,
                              void* d_out, int out_size, void* d_ws, size_t ws_size,
                              hipStream_t stream)
{
  fp x  = (fp)d_in[0];
  fp A  = (fp)d_in[1];
  fp W  = (fp)d_in[2];
  fp b  = (fp)d_in[3];
  fp g0 = (fp)d_in[4];
  fp b0 = (fp)d_in[5];
  fp g1 = (fp)d_in[6];
  fp b1 = (fp)d_in[7];
  fp cw = (fp)d_in[8];
  fp cb = (fp)d_in[9];
  fp g2 = (fp)d_in[10];
  fp b2 = (fp)d_in[11];
  // d_in[12] = keep_prob == 1 -> DropBlocks identity.

  char* ws = (char*)d_ws;
  float*          normA = (float*)(ws + 0);
  float*          Weff  = (float*)(ws + 67584);
  float*          beff  = (float*)(ws + 116736);
  float*          cbe   = (float*)(ws + 117504);
  unsigned short* cwetb = (unsigned short*)(ws + 117760);
  float*          biasU = (float*)(ws + 191488);
  unsigned short* U     = (unsigned short*)(ws + 197888);
  unsigned short* xb    = (unsigned short*)(ws + 5932288);
  unsigned short* yb    = (unsigned short*)(ws + 32146688);

  k_pre<<<259, 256, 0, stream>>>(A, W, b, g0, b0, cw, cb, g2, b2,
                                 normA, Weff, beff, cbe, cwetb);
  k_pre2<<<1792, 256, 0, stream>>>(Weff, beff, normA, g1, b1, U, biasU);
  k_xt<<<1024, 256, 0, stream>>>(x, xb);
  k_gemm<<<448, 256, 0, stream>>>(U, xb, biasU, yb);
  k_tcn<<<1024, 256, 0, stream>>>(yb, cwetb, cbe, x, (float*)d_out);
}

// Round 8
// 226.506 us; speedup vs baseline: 1.1608x; 1.0627x over previous
//
#include <hip/hip_runtime.h>
#include <hip/hip_bf16.h>
#include <stdint.h>

// Shapes: N=32, CIN=COUT=64, T=256, V=25, K3=3, G=8
// GCN folded to one GEMM: M=1600 (m=w*64+c), K=1600 (k=cin*25+v), N=8192 (n,t)
//   residual (+x) folded into U's diagonal: U[w*64+c][c*25+w] += 1
// k_gemm: 256m x 128n tiles, private-A wave strips
// k_tcn: MFMA im2col, 512-thread blocks (16 waves/CU), DMA staging
//   OOB window rows read from U's pad rows (zeroed by k_pre2 every call)

typedef const float* fp;
typedef __attribute__((ext_vector_type(8))) short short8;   // 8 bf16 (4 VGPRs)
typedef __attribute__((ext_vector_type(4))) float floatx4;  // MFMA acc

__device__ __forceinline__ float us2f(unsigned int u){
  union { unsigned int i; float f; } c; c.i = u << 16; return c.f;
}
__device__ __forceinline__ unsigned short f2us(float f){
  __hip_bfloat16 h = __float2bfloat16(f);
  return *reinterpret_cast<unsigned short*>(&h);
}
__device__ __forceinline__ void gload_lds16(const void* g, void* l){
  __builtin_amdgcn_global_load_lds(
      (const __attribute__((address_space(1))) void*)g,
      (__attribute__((address_space(3))) void*)l, 16, 0, 0);
}

// ---------------- workspace layout (bytes) ----------------
// normA fp32 [3][8][25][28] @ 0         (67200)
// Weff  fp32 [64][192]      @ 67584     (49152)
// beff  fp32 [192]          @ 116736    (768)
// cbe   fp32 [64]           @ 117504    (256)
// cwetb bf16 [64][9][64]    @ 117760    (73728)
// biasU fp32 [1600]         @ 191488    (6400)
// U     bf16 [1792][1600]   @ 197888    (5734400)  rows 1600+ = zero page
// xb    bf16 [32][256][1600]@ 5932288   (26214400)
// yb    bf16 [32][256][1600]@ 32146688  (26214400)   total ~58.4 MB

// ---------------- pre 1: BN folds + adjacency normalize ----------------
__global__ __launch_bounds__(256) void k_pre(
    fp A, fp W, fp b, fp g0, fp b0, fp cw, fp cb, fp g2, fp b2,
    float* normA, float* Weff, float* beff, float* cbe, unsigned short* cwetb)
{
  int gid = blockIdx.x * 256 + threadIdx.x;
  const float inv_s = rsqrtf(1.0f + 1e-5f);

  if (gid < 16800) {                      // normA[k][g][v][w pad28]
    int k  = gid / 5600;
    int r  = gid % 5600;
    int g  = r / 700;
    int r2 = r % 700;
    int v  = r2 / 28, w = r2 % 28;
    float val = 0.f;
    if (w < 25) {
      float s = 0.f;
      for (int vv = 0; vv < 25; vv++) s += A[((k*8+g)*25+vv)*25 + w];
      val = A[((k*8+g)*25+v)*25 + w] / (s + 0.001f);
    }
    normA[gid] = val;
    return;
  }
  gid -= 16800;
  if (gid < 12288) {                      // Weff[cin][192]
    int d = gid % 192;
    Weff[gid] = W[gid] * (g0[d] * inv_s);
    return;
  }
  gid -= 12288;
  if (gid < 192) {                        // beff
    beff[gid] = b[gid] * (g0[gid] * inv_s) + b0[gid];
    return;
  }
  gid -= 192;
  if (gid < 64) {                         // cbe
    cbe[gid] = cb[gid] * (g2[gid] * inv_s) + b2[gid];
    return;
  }
  gid -= 64;
  if (gid < 36864) {                      // cwetb[o][j][i] bf16
    int o = gid / 576, r = gid % 576;
    int j = r / 64, i = r % 64;
    cwetb[gid] = f2us(cw[(o*64+i)*9 + j] * (g2[o] * inv_s));
  }
}

// ---------------- pre 2: U rows via LDS-cached factors ----------------
__global__ __launch_bounds__(256) void k_pre2(
    const float* Weff, const float* beff, const float* normA, fp g1, fp b1,
    unsigned short* U, float* biasU)
{
  int m = blockIdx.x;                     // 1792 blocks
  int tid = threadIdx.x;
  if (m >= 1600) {                        // zero-pad rows (also k_tcn zero page)
    for (int k = tid; k < 1600; k += 256) U[(long long)m*1600 + k] = 0;
    return;
  }
  int c = m & 63, w = m >> 6, g = c & 7;
  __shared__ float nAL[75];               // [kk][vv] = normA[kk,g,vv,w]
  __shared__ float WeffL[192];            // [kk][cin]
  if (tid < 75) {
    int kk = tid / 25, vv = tid % 25;
    nAL[tid] = normA[((kk*8 + g)*25 + vv)*28 + w];
  }
  if (tid < 192) {
    int kk = tid >> 6, cin = tid & 63;
    WeffL[tid] = Weff[cin*192 + kk*64 + c];
  }
  __syncthreads();
  float s1 = g1[c] * rsqrtf(1.0f + 1e-5f);
  for (int k = tid; k < 1600; k += 256) {
    int cin = k / 25, vv = k - cin*25;
    float acc = WeffL[cin]       * nAL[vv]
              + WeffL[64 + cin]  * nAL[25 + vv]
              + WeffL[128 + cin] * nAL[50 + vv];
    acc *= s1;
    if (cin == c && vv == w) acc += 1.0f;  // residual folded into diagonal
    U[(long long)m*1600 + k] = f2us(acc);
  }
  if (tid == 0) {
    float acc = 0.f;
    for (int kk = 0; kk < 3; kk++) {
      float be = beff[kk*64 + c];
      for (int v = 0; v < 25; v++) acc += be * nAL[kk*25 + v];
    }
    biasU[m] = acc * s1 + b1[c];
  }
}

// ---------------- transpose x -> bf16 [n][t][cin*25+v] (LDS, coalesced) ----
__global__ __launch_bounds__(256) void k_xt(fp x, unsigned short* xb)
{
  int n = blockIdx.x >> 5, tb = blockIdx.x & 31, t0 = tb*8, tid = threadIdx.x;
  __shared__ unsigned short xs[64*8*26];
  for (int e = tid; e < 12800; e += 256) {
    int c = e / 200, r = e - c*200, tt = r / 25, v = r - tt*25;
    xs[(c*8 + tt)*26 + v] = f2us(x[((n*64 + c)*256 + t0 + tt)*25 + v]);
  }
  __syncthreads();
  for (int e = tid; e < 12800; e += 256) {
    int tt = e / 1600, q = e - tt*1600, c = q / 25, v = q - c*25;
    xb[(n*256 + t0 + tt)*1600 + q] = xs[(c*8 + tt)*26 + v];
  }
}

// ---------------- GCN GEMM: 256m x 128n, private-A wave strips ----------
__global__ __launch_bounds__(256, 2) void k_gemm(
    const unsigned short* U, const unsigned short* xb, const float* biasU,
    unsigned short* yb)
{
  int bm = blockIdx.x >> 6, bn = blockIdx.x & 63;   // 7 x 64
  int n = bn >> 1, t0 = (bn & 1) * 128;
  int tid = threadIdx.x, lane = tid & 63, wid = tid >> 6;
  int l15 = lane & 15, grp = lane >> 4;

  __shared__ __align__(16) unsigned short As[256*64];  // 32 KB
  __shared__ __align__(16) unsigned short Bs[128*64];  // 16 KB

  const unsigned short* gA[8];
  const unsigned short* gB[4];
  unsigned short* lA[8];
  unsigned short* lB[4];
  #pragma unroll
  for (int it = 0; it < 8; it++) {
    int e = it*256 + tid;
    int row = e >> 3, li = e & 7;
    int kcol = (li ^ (row & 7)) * 8;       // XOR swizzle on global source side
    gA[it] = U + (long long)(bm*256 + row)*1600 + kcol;
    lA[it] = As + e*8;
  }
  #pragma unroll
  for (int it = 0; it < 4; it++) {
    int e = it*256 + tid;
    int row = e >> 3, li = e & 7;
    int kcol = (li ^ (row & 7)) * 8;
    gB[it] = xb + (long long)(n*256 + t0 + row)*1600 + kcol;
    lB[it] = Bs + e*8;
  }

  floatx4 acc[4][8];
  #pragma unroll
  for (int i = 0; i < 4; i++)
    #pragma unroll
    for (int j = 0; j < 8; j++) acc[i][j] = (floatx4){0.f,0.f,0.f,0.f};

  for (int kc = 0; kc < 25; kc++) {
    #pragma unroll
    for (int it = 0; it < 8; it++) gload_lds16(gA[it] + kc*64, lA[it]);
    #pragma unroll
    for (int it = 0; it < 4; it++) gload_lds16(gB[it] + kc*64, lB[it]);
    __syncthreads();
    #pragma unroll
    for (int ks = 0; ks < 2; ks++) {
      int colk = ((ks*4 + grp) ^ (l15 & 7)) * 8;   // un-swizzle at read
      short8 af[4], bf[8];
      #pragma unroll
      for (int i = 0; i < 4; i++)
        af[i] = *(const short8*)(As + (wid*64 + i*16 + l15)*64 + colk);
      #pragma unroll
      for (int j = 0; j < 8; j++)
        bf[j] = *(const short8*)(Bs + (j*16 + l15)*64 + colk);
      #pragma unroll
      for (int i = 0; i < 4; i++)
        #pragma unroll
        for (int j = 0; j < 8; j++)
          acc[i][j] = __builtin_amdgcn_mfma_f32_16x16x32_bf16(af[i], bf[j], acc[i][j], 0, 0, 0);
    }
    __syncthreads();
  }

  #pragma unroll
  for (int i = 0; i < 4; i++) {
    int mbase = bm*256 + wid*64 + i*16 + grp*4;
    if (mbase >= 1600) continue;
    float4 bu = *(const float4*)(biasU + mbase);
    #pragma unroll
    for (int j = 0; j < 8; j++) {
      int col = j*16 + l15;
      int t = t0 + col;
      ushort4 pk;
      pk.x = f2us(fmaxf(acc[i][j][0] + bu.x, 0.f));
      pk.y = f2us(fmaxf(acc[i][j][1] + bu.y, 0.f));
      pk.z = f2us(fmaxf(acc[i][j][2] + bu.z, 0.f));
      pk.w = f2us(fmaxf(acc[i][j][3] + bu.w, 0.f));
      *(ushort4*)(yb + (long long)(n*256 + t)*1600 + mbase) = pk;
    }
  }
}

// ---------------- TCN as MFMA: 512 threads, DMA staging, tile split ----------
// 8 waves share one 57 KB window; wave pair (p, p+4) owns o-strip p*16 and
// splits the 13 col-tiles even/odd. Staging via global_load_lds (linear
// deposit = wave-uniform base + lane*16); OOB rows source from zpg (U pad
// rows, zeroed by k_pre2 each call) so every DMA issues with full exec.
__global__ __launch_bounds__(512) void k_tcn(
    const unsigned short* yb, const unsigned short* cwetb, const float* cbe,
    fp x, const unsigned short* zpg, float* out)
{
  int n = blockIdx.x >> 5, tb = blockIdx.x & 31, t0 = tb*8;
  int tid = threadIdx.x, lane = tid & 63, wid = tid >> 6;
  int l15 = lane & 15, grp = lane >> 4;
  __shared__ __align__(16) unsigned short ys[3584*8];  // 57344 B (425 rows + pad)

  #pragma unroll
  for (int it = 0; it < 7; it++) {
    int e = it*512 + tid;                 // e < 3584, always full exec
    int row = e >> 3, li = e & 7;
    int rt = row / 25, v = row - rt*25;
    int tg = t0 - 4 + rt;
    int sli = li ^ (row & 7);             // fetch swizzled i-group
    bool ok = (row < 425) && (tg >= 0) && (tg < 256);
    const unsigned short* src = ok
      ? yb + ((long long)(n*256 + tg)*1600 + v*64 + sli*8)
      : zpg + li*8;
    gload_lds16(src, ys + e*8);           // linear LDS deposit
  }

  // A-frags: conv weights in registers, o-strip p = wid&3, half h = wid>>2
  int p = wid & 3, h = wid >> 2;
  int o0 = p * 16;
  int o = o0 + l15;
  short8 af[9][2];
  #pragma unroll
  for (int j = 0; j < 9; j++) {
    af[j][0] = *(const short8*)(cwetb + ((o*9 + j)*64 + grp*8));
    af[j][1] = *(const short8*)(cwetb + ((o*9 + j)*64 + 32 + grp*8));
  }
  float4 cb4 = *(const float4*)(cbe + o0 + grp*4);
  __syncthreads();

  for (int tile = h; tile < 13; tile += 2) {
    int colb = tile*16 + l15;
    floatx4 acc = (floatx4){0.f,0.f,0.f,0.f};
    #pragma unroll
    for (int j = 0; j < 9; j++) {
      int row = colb + 25*j;
      int r7 = row & 7;
      const unsigned short* rb = ys + row*64;
      short8 b0 = *(const short8*)(rb + ((grp     ^ r7))*8);
      short8 b1 = *(const short8*)(rb + (((4+grp) ^ r7))*8);
      acc = __builtin_amdgcn_mfma_f32_16x16x32_bf16(af[j][0], b0, acc, 0, 0, 0);
      acc = __builtin_amdgcn_mfma_f32_16x16x32_bf16(af[j][1], b1, acc, 0, 0, 0);
    }
    if (colb < 200) {
      int tt = colb / 25, v = colb - tt*25, t = t0 + tt;
      #pragma unroll
      for (int r = 0; r < 4; r++) {
        int oo = o0 + grp*4 + r;
        float val = acc[r] + ((const float*)&cb4)[r]
                  + x[((n*64 + oo)*256 + t)*25 + v];
        out[((n*64 + oo)*256 + t)*25 + v] = fmaxf(val, 0.f);
      }
    }
  }
}

extern "C" void kernel_launch(void* const* d_in, const int* in_sizes, int n_in,
                              void* d_out, int out_size, void* d_ws, size_t ws_size,
                              hipStream_t stream)
{
  fp x  = (fp)d_in[0];
  fp A  = (fp)d_in[1];
  fp W  = (fp)d_in[2];
  fp b  = (fp)d_in[3];
  fp g0 = (fp)d_in[4];
  fp b0 = (fp)d_in[5];
  fp g1 = (fp)d_in[6];
  fp b1 = (fp)d_in[7];
  fp cw = (fp)d_in[8];
  fp cb = (fp)d_in[9];
  fp g2 = (fp)d_in[10];
  fp b2 = (fp)d_in[11];
  // d_in[12] = keep_prob == 1 -> DropBlocks identity.

  char* ws = (char*)d_ws;
  float*          normA = (float*)(ws + 0);
  float*          Weff  = (float*)(ws + 67584);
  float*          beff  = (float*)(ws + 116736);
  float*          cbe   = (float*)(ws + 117504);
  unsigned short* cwetb = (unsigned short*)(ws + 117760);
  float*          biasU = (float*)(ws + 191488);
  unsigned short* U     = (unsigned short*)(ws + 197888);
  unsigned short* xb    = (unsigned short*)(ws + 5932288);
  unsigned short* yb    = (unsigned short*)(ws + 32146688);
  const unsigned short* zpg = U + (long long)1600*1600;  // zeroed pad rows

  k_pre<<<259, 256, 0, stream>>>(A, W, b, g0, b0, cw, cb, g2, b2,
                                 normA, Weff, beff, cbe, cwetb);
  k_pre2<<<1792, 256, 0, stream>>>(Weff, beff, normA, g1, b1, U, biasU);
  k_xt<<<1024, 256, 0, stream>>>(x, xb);
  k_gemm<<<448, 256, 0, stream>>>(U, xb, biasU, yb);
  k_tcn<<<1024, 512, 0, stream>>>(yb, cwetb, cbe, x, zpg, (float*)d_out);
}